// Round 1
// baseline (7790.457 us; speedup 1.0000x reference)
//
#include <hip/hip_runtime.h>

#define NEG_SLOPE 0.2f

// ---------------- dense per-row GEMM: out[r, :H] = f(x[r, :DIN]) @ W -----------
template<int DIN, int H, bool RELU_IN>
__global__ void gemm_rows(const float* __restrict__ x, const float* __restrict__ W,
                          float* __restrict__ out, int nRows) {
    __shared__ float sW[DIN * H];
    for (int i = threadIdx.x; i < DIN * H; i += blockDim.x) sW[i] = W[i];
    __syncthreads();
    int row = blockIdx.x * blockDim.x + threadIdx.x;
    if (row >= nRows) return;
    const float* xr = x + (size_t)row * DIN;
    float acc[H];
#pragma unroll
    for (int c = 0; c < H; ++c) acc[c] = 0.f;
#pragma unroll
    for (int k = 0; k < DIN; ++k) {
        float xv = xr[k];
        if (RELU_IN) xv = xv > 0.f ? xv : NEG_SLOPE * xv;
#pragma unroll
        for (int c = 0; c < H; ++c) acc[c] += xv * sW[k * H + c];
    }
    float* o = out + (size_t)row * H;
#pragma unroll
    for (int c = 0; c < H; ++c) o[c] = acc[c];
}

// ------------- edge scatter: dst[b, srow[e], :] += src[b, gcol[e], :] * coef[e] -
// D4 = channels/4. One thread handles one (edge, 4-channel group) for batch blockIdx.y.
template<int D4, bool USE_DIAG>
__global__ void scatter_edges(const float* __restrict__ src, float* __restrict__ dst,
                              const int* __restrict__ srows, const int* __restrict__ gcols,
                              const float* __restrict__ vals, const float* __restrict__ diag,
                              int E, int srcRows, int dstRows) {
    int idx = blockIdx.x * blockDim.x + threadIdx.x;
    if (idx >= E * D4) return;
    int e  = idx / D4;
    int cg = idx - e * D4;
    int b  = blockIdx.y;
    int gi = gcols[e];
    int si = srows[e];
    float v = vals[e];
    if (USE_DIAG) v *= diag[gi];
    const float4* sp = (const float4*)(src + ((size_t)b * srcRows + gi) * (D4 * 4));
    float4 m = sp[cg];
    float* dp = dst + ((size_t)b * dstRows + si) * (D4 * 4) + cg * 4;
    atomicAdd(dp + 0, m.x * v);
    atomicAdd(dp + 1, m.y * v);
    atomicAdd(dp + 2, m.z * v);
    atomicAdd(dp + 3, m.w * v);
}

// ---------------- heads: out[b,0]=lrelu(x2[b,N-2,:])@w1+b1 ; out[b,1]=... -------
__global__ void final_heads(const float* __restrict__ x2,
                            const float* __restrict__ w1, const float* __restrict__ b1,
                            const float* __restrict__ w2, const float* __restrict__ b2,
                            float* __restrict__ out, int N, int B) {
    int i = threadIdx.x;
    if (i >= 2 * B) return;
    int b = i >> 1, which = i & 1;
    int row = N - 2 + which;
    const float* xr = x2 + ((size_t)b * N + row) * 16;
    const float* w = which ? w2 : w1;
    float acc = which ? b2[0] : b1[0];
    for (int k = 0; k < 16; ++k) {
        float xv = xr[k];
        xv = xv > 0.f ? xv : NEG_SLOPE * xv;
        acc += xv * w[k];
    }
    out[b * 2 + which] = acc;
}

extern "C" void kernel_launch(void* const* d_in, const int* in_sizes, int n_in,
                              void* d_out, int out_size, void* d_ws, size_t ws_size,
                              hipStream_t stream) {
    const int*   w_idx  = (const int*)d_in[0];     // (2,E): rows [0:E] in R, cols [E:2E] in N
    const float* w_val  = (const float*)d_in[1];
    const int*   wi_idx = (const int*)d_in[2];     // (2,E): rows [0:E] in N, cols [E:2E] in R
    const float* wi_val = (const float*)d_in[3];
    const float* x      = (const float*)d_in[4];   // (B,N,32)
    const float* W1     = (const float*)d_in[5];   // (32,32)
    const float* diag1  = (const float*)d_in[6];   // (R,)
    const float* W2     = (const float*)d_in[7];   // (32,16)
    const float* diag2  = (const float*)d_in[8];   // (R,)
    const float* rw1    = (const float*)d_in[9];
    const float* rb1    = (const float*)d_in[10];
    const float* rw2    = (const float*)d_in[11];
    const float* rb2    = (const float*)d_in[12];
    float* out = (float*)d_out;

    const int B = 4, N = 50000, R = 100000, E = 1600000;

    float* h_buf = (float*)d_ws;                       // B*N*32 floats (25.6 MB)
    float* t_buf = h_buf + (size_t)B * N * 32;         // B*R*32 floats (51.2 MB)
    float* o_buf = t_buf + (size_t)B * R * 32;         // B*N*32 floats (25.6 MB)

    const int rows = B * N;
    const int blk = 256;

    // ---------------- layer 1 (32 channels) ----------------
    hipMemsetAsync(t_buf, 0, (size_t)B * R * 32 * sizeof(float), stream);
    gemm_rows<32, 32, false><<<(rows + blk - 1) / blk, blk, 0, stream>>>(x, W1, h_buf, rows);
    {
        dim3 g((E * 8 + blk - 1) / blk, B);
        scatter_edges<8, false><<<g, blk, 0, stream>>>(h_buf, t_buf, w_idx, w_idx + E,
                                                       w_val, nullptr, E, N, R);
    }
    hipMemsetAsync(o_buf, 0, (size_t)B * N * 32 * sizeof(float), stream);
    {
        dim3 g((E * 8 + blk - 1) / blk, B);
        scatter_edges<8, true><<<g, blk, 0, stream>>>(t_buf, o_buf, wi_idx, wi_idx + E,
                                                      wi_val, diag1, E, R, N);
    }

    // ---------------- layer 2 (16 channels), leaky-relu fused into gemm input ---
    hipMemsetAsync(t_buf, 0, (size_t)B * R * 16 * sizeof(float), stream);
    gemm_rows<32, 16, true><<<(rows + blk - 1) / blk, blk, 0, stream>>>(o_buf, W2, h_buf, rows);
    {
        dim3 g((E * 4 + blk - 1) / blk, B);
        scatter_edges<4, false><<<g, blk, 0, stream>>>(h_buf, t_buf, w_idx, w_idx + E,
                                                       w_val, nullptr, E, N, R);
    }
    hipMemsetAsync(o_buf, 0, (size_t)B * N * 16 * sizeof(float), stream);
    {
        dim3 g((E * 4 + blk - 1) / blk, B);
        scatter_edges<4, true><<<g, blk, 0, stream>>>(t_buf, o_buf, wi_idx, wi_idx + E,
                                                      wi_val, diag2, E, R, N);
    }

    // ---------------- heads ----------------
    final_heads<<<1, 64, 0, stream>>>(o_buf, rw1, rb1, rw2, rb2, out, N, B);
}

// Round 2
// 1001.192 us; speedup vs baseline: 7.7812x; 7.7812x over previous
//
#include <hip/hip_runtime.h>

#define NEG_SLOPE 0.2f

static const int B = 4, N = 50000, R = 100000, E = 1600000;

// ---------------- dense per-row GEMM: out[r, :H] = f(x[r, :DIN]) @ W -----------
template<int DIN, int H, bool RELU_IN, bool USE_FLAG>
__global__ void gemm_rows(const float* __restrict__ x, const float* __restrict__ W,
                          float* __restrict__ out, int nRows,
                          const int* __restrict__ flag, int rowsPerBatch) {
    __shared__ float sW[DIN * H];
    for (int i = threadIdx.x; i < DIN * H; i += blockDim.x) sW[i] = W[i];
    __syncthreads();
    int row = blockIdx.x * blockDim.x + threadIdx.x;
    if (row >= nRows) return;
    if (USE_FLAG) {
        int n = row % rowsPerBatch;
        if (!flag[n]) return;
    }
    const float* xr = x + (size_t)row * DIN;
    float acc[H];
#pragma unroll
    for (int c = 0; c < H; ++c) acc[c] = 0.f;
#pragma unroll
    for (int k = 0; k < DIN; ++k) {
        float xv = xr[k];
        if (RELU_IN) xv = xv > 0.f ? xv : NEG_SLOPE * xv;
#pragma unroll
        for (int c = 0; c < H; ++c) acc[c] += xv * sW[k * H + c];
    }
    float* o = out + (size_t)row * H;
#pragma unroll
    for (int c = 0; c < H; ++c) o[c] = acc[c];
}

// ---------------- CSR build ----------------
__global__ void hist_kernel(const int* __restrict__ rows, int* __restrict__ cnt, int e) {
    int i = blockIdx.x * blockDim.x + threadIdx.x;
    if (i < e) atomicAdd(&cnt[rows[i]], 1);
}

template<int NTH>
__global__ void scan_kernel(const int* __restrict__ cnt, int n, int* __restrict__ off) {
    __shared__ int base[NTH + 1];
    int chunk = (n + NTH - 1) / NTH;
    int start = threadIdx.x * chunk;
    int end = start + chunk; if (end > n) end = n; if (start > n) start = n;
    int s = 0;
    for (int i = start; i < end; ++i) s += cnt[i];
    __shared__ int partial[NTH];
    partial[threadIdx.x] = s;
    __syncthreads();
    if (threadIdx.x == 0) {
        int acc = 0;
        for (int i = 0; i < NTH; ++i) { base[i] = acc; acc += partial[i]; }
        base[NTH] = acc;
    }
    __syncthreads();
    int acc = base[threadIdx.x];
    for (int i = start; i < end; ++i) { off[i] = acc; acc += cnt[i]; }
    if (threadIdx.x == NTH - 1) off[n] = base[NTH];
}

__global__ void place_kernel(const int* __restrict__ rows, const int* __restrict__ off,
                             int* __restrict__ cursor, int* __restrict__ eid, int e) {
    int i = blockIdx.x * blockDim.x + threadIdx.x;
    if (i >= e) return;
    int r = rows[i];
    int pos = off[r] + atomicAdd(&cursor[r], 1);
    eid[pos] = i;
}

// ---------------- frontier marking (edge scans) ----------------
// markA: wavelets_inverse rows N-2/N-1 -> flagR2[col]
__global__ void markA(const int* __restrict__ wi_rows, const int* __restrict__ wi_cols,
                      int* __restrict__ flagR2, int e, int n) {
    int i = blockIdx.x * blockDim.x + threadIdx.x;
    if (i >= e) return;
    if (wi_rows[i] >= n - 2) flagR2[wi_cols[i]] = 1;
}
// markB: wavelets rows with flagR2 -> flagN1[col]
__global__ void markB(const int* __restrict__ w_rows, const int* __restrict__ w_cols,
                      const int* __restrict__ flagR2, int* __restrict__ flagN1, int e) {
    int i = blockIdx.x * blockDim.x + threadIdx.x;
    if (i >= e) return;
    if (flagR2[w_rows[i]]) flagN1[w_cols[i]] = 1;
}
// markC: wavelets_inverse rows with flagN1 -> flagR1[col]
__global__ void markC(const int* __restrict__ wi_rows, const int* __restrict__ wi_cols,
                      const int* __restrict__ flagN1, int* __restrict__ flagR1, int e) {
    int i = blockIdx.x * blockDim.x + threadIdx.x;
    if (i >= e) return;
    if (flagN1[wi_rows[i]]) flagR1[wi_cols[i]] = 1;
}

// ------------- flag-gated CSR gather: dst[b,row,:] = sum_e val[e]*src[b,col[e],:] --
template<int C>
__global__ void gather_rows(const float* __restrict__ src, float* __restrict__ dst,
                            const int* __restrict__ off, const int* __restrict__ eids,
                            const int* __restrict__ cols, const float* __restrict__ vals,
                            const int* __restrict__ flag, int nRows, int srcN) {
    int tid = blockIdx.x * blockDim.x + threadIdx.x;
    int g = tid / C;
    int c = tid - g * C;
    int row = g / B;
    int b = g - row * B;
    if (row >= nRows) return;
    if (!flag[row]) return;
    int s = off[row], en = off[row + 1];
    float acc = 0.f;
    for (int i = s; i < en; ++i) {
        int eid = eids[i];
        float v = vals[eid];
        int col = cols[eid];
        acc += v * src[((size_t)b * srcN + col) * C + c];
    }
    dst[((size_t)b * nRows + row) * C + c] = acc;
}

// ------------- x1 scatter: sparse-flagged edges, atomics (tiny fraction passes) ---
__global__ void x1_scatter(const float* __restrict__ t1, float* __restrict__ x1,
                           const int* __restrict__ wi_rows, const int* __restrict__ wi_cols,
                           const float* __restrict__ wi_val, const float* __restrict__ diag,
                           const int* __restrict__ flagN1, int e) {
    int idx = blockIdx.x * blockDim.x + threadIdx.x;
    if (idx >= e * B) return;
    int ed = idx >> 2;      // B == 4
    int b = idx & 3;
    int row = wi_rows[ed];
    if (!flagN1[row]) return;
    int col = wi_cols[ed];
    float coef = wi_val[ed] * diag[col];
    const float* sp = t1 + ((size_t)b * R + col) * 32;
    float* dp = x1 + ((size_t)b * N + row) * 32;
#pragma unroll
    for (int c = 0; c < 32; ++c) atomicAdd(dp + c, coef * sp[c]);
}

// ------------- x2 accumulation: edges into rows N-2/N-1 (few pass) ---------------
__global__ void x2_scan(const float* __restrict__ t2, float* __restrict__ x2buf,
                        const int* __restrict__ wi_rows, const int* __restrict__ wi_cols,
                        const float* __restrict__ wi_val, const float* __restrict__ diag,
                        int e, int n) {
    int ed = blockIdx.x * blockDim.x + threadIdx.x;
    if (ed >= e) return;
    int row = wi_rows[ed];
    if (row < n - 2) return;
    int which = row - (n - 2);
    int col = wi_cols[ed];
    float coef = wi_val[ed] * diag[col];
#pragma unroll
    for (int b = 0; b < B; ++b) {
        const float* sp = t2 + ((size_t)b * R + col) * 16;
        float* dp = x2buf + (b * 2 + which) * 16;
#pragma unroll
        for (int c = 0; c < 16; ++c) atomicAdd(dp + c, coef * sp[c]);
    }
}

// ---------------- heads ----------------
__global__ void heads_kernel(const float* __restrict__ x2buf,
                             const float* __restrict__ w1, const float* __restrict__ b1,
                             const float* __restrict__ w2, const float* __restrict__ b2,
                             float* __restrict__ out) {
    int i = threadIdx.x;
    if (i >= 2 * B) return;
    int b = i >> 1, which = i & 1;
    const float* xr = x2buf + (b * 2 + which) * 16;
    const float* w = which ? w2 : w1;
    float acc = which ? b2[0] : b1[0];
    for (int k = 0; k < 16; ++k) {
        float xv = xr[k];
        xv = xv > 0.f ? xv : NEG_SLOPE * xv;
        acc += xv * w[k];
    }
    out[b * 2 + which] = acc;
}

extern "C" void kernel_launch(void* const* d_in, const int* in_sizes, int n_in,
                              void* d_out, int out_size, void* d_ws, size_t ws_size,
                              hipStream_t stream) {
    const int*   w_rows  = (const int*)d_in[0];        // (2,E): [0:E] rows in R
    const int*   w_cols  = ((const int*)d_in[0]) + E;  //        [E:2E] cols in N
    const float* w_val   = (const float*)d_in[1];
    const int*   wi_rows = (const int*)d_in[2];        // (2,E): [0:E] rows in N
    const int*   wi_cols = ((const int*)d_in[2]) + E;  //        [E:2E] cols in R
    const float* wi_val  = (const float*)d_in[3];
    const float* x       = (const float*)d_in[4];      // (B,N,32)
    const float* W1      = (const float*)d_in[5];      // (32,32)
    const float* diag1   = (const float*)d_in[6];      // (R,)
    const float* W2      = (const float*)d_in[7];      // (32,16)
    const float* diag2   = (const float*)d_in[8];      // (R,)
    const float* rw1     = (const float*)d_in[9];
    const float* rb1     = (const float*)d_in[10];
    const float* rw2     = (const float*)d_in[11];
    const float* rb2     = (const float*)d_in[12];
    float* out = (float*)d_out;

    // ---------------- workspace layout ----------------
    float* h1   = (float*)d_ws;                 // B*N*32 = 6.4M floats; reused as x1
    float* treg = h1 + (size_t)B * N * 32;      // 12.8M floats: t1; later h2 (+0), t2 (+3.2M)
    int* csr_off = (int*)(treg + (size_t)B * R * 32);  // R+1
    int* csr_cnt = csr_off + (R + 1);                  // R (counts, then cursor)
    int* csr_eid = csr_cnt + R;                        // E
    int* flagR2  = csr_eid + E;                        // R
    int* flagN1  = flagR2 + R;                         // N
    int* flagR1  = flagN1 + N;                         // R
    float* x2buf = (float*)(flagR1 + R);               // 2*B*16 = 128 floats

    float* x1 = h1;                       // alias (h1 dead after t1 gather)
    float* h2 = treg;                     // B*N*16 = 3.2M floats
    float* t2 = treg + (size_t)B * N * 16;// B*R*16 = 6.4M floats

    const int blk = 256;
    const int egrid = (E + blk - 1) / blk;

    // zero counters + flags + x2buf (flags are contiguous)
    hipMemsetAsync(csr_cnt, 0, (size_t)R * sizeof(int), stream);
    hipMemsetAsync(flagR2, 0, (size_t)(R + N + R) * sizeof(int), stream);
    hipMemsetAsync(x2buf, 0, 2 * B * 16 * sizeof(float), stream);

    // ---- CSR build for wavelets (dest rows in R) ----
    hist_kernel<<<egrid, blk, 0, stream>>>(w_rows, csr_cnt, E);
    scan_kernel<1024><<<1, 1024, 0, stream>>>(csr_cnt, R, csr_off);
    hipMemsetAsync(csr_cnt, 0, (size_t)R * sizeof(int), stream);
    place_kernel<<<egrid, blk, 0, stream>>>(w_rows, csr_off, csr_cnt, csr_eid, E);

    // ---- frontier marking ----
    markA<<<egrid, blk, 0, stream>>>(wi_rows, wi_cols, flagR2, E, N);
    markB<<<egrid, blk, 0, stream>>>(w_rows, w_cols, flagR2, flagN1, E);
    markC<<<egrid, blk, 0, stream>>>(wi_rows, wi_cols, flagN1, flagR1, E);

    // ---- layer 1 ----
    gemm_rows<32, 32, false, false><<<(B * N + blk - 1) / blk, blk, 0, stream>>>(
        x, W1, h1, B * N, nullptr, N);
    {   // t1 at flagR1 rows: gather, no atomics, no zero-init
        int threads = R * B * 32;
        gather_rows<32><<<(threads + blk - 1) / blk, blk, 0, stream>>>(
            h1, treg, csr_off, csr_eid, w_cols, w_val, flagR1, R, N);
    }
    hipMemsetAsync(x1, 0, (size_t)B * N * 32 * sizeof(float), stream);  // h1 dead now
    x1_scatter<<<(E * B + blk - 1) / blk, blk, 0, stream>>>(
        treg, x1, wi_rows, wi_cols, wi_val, diag1, flagN1, E);

    // ---- layer 2 (lrelu on x1 fused into gemm input) ----
    gemm_rows<32, 16, true, true><<<(B * N + blk - 1) / blk, blk, 0, stream>>>(
        x1, W2, h2, B * N, flagN1, N);
    {   // t2 at flagR2 rows
        int threads = R * B * 16;
        gather_rows<16><<<(threads + blk - 1) / blk, blk, 0, stream>>>(
            h2, t2, csr_off, csr_eid, w_cols, w_val, flagR2, R, N);
    }
    x2_scan<<<egrid, blk, 0, stream>>>(t2, x2buf, wi_rows, wi_cols, wi_val, diag2, E, N);
    heads_kernel<<<1, 64, 0, stream>>>(x2buf, rw1, rb1, rw2, rb2, out);
}

// Round 3
// 429.383 us; speedup vs baseline: 18.1434x; 2.3317x over previous
//
#include <hip/hip_runtime.h>

#define NEG_SLOPE 0.2f

static const int B = 4, N = 50000, R = 100000, E = 1600000;
static const int WI_CAP = 512 * 1024;   // packed wi-CSR capacity (actual ~32k, 16x margin)

// ---------------- dense per-row GEMM: out[r, :H] = f(x[r, :DIN]) @ W -----------
template<int DIN, int H, bool RELU_IN, bool USE_FLAG>
__global__ void gemm_rows(const float* __restrict__ x, const float* __restrict__ W,
                          float* __restrict__ out, int nRows,
                          const int* __restrict__ flag, int rowsPerBatch) {
    __shared__ float sW[DIN * H];
    for (int i = threadIdx.x; i < DIN * H; i += blockDim.x) sW[i] = W[i];
    __syncthreads();
    int row = blockIdx.x * blockDim.x + threadIdx.x;
    if (row >= nRows) return;
    if (USE_FLAG) {
        int n = row % rowsPerBatch;
        if (!flag[n]) return;
    }
    const float* xr = x + (size_t)row * DIN;
    float acc[H];
#pragma unroll
    for (int c = 0; c < H; ++c) acc[c] = 0.f;
#pragma unroll
    for (int k = 0; k < DIN; ++k) {
        float xv = xr[k];
        if (RELU_IN) xv = xv > 0.f ? xv : NEG_SLOPE * xv;
#pragma unroll
        for (int c = 0; c < H; ++c) acc[c] += xv * sW[k * H + c];
    }
    float* o = out + (size_t)row * H;
#pragma unroll
    for (int c = 0; c < H; ++c) o[c] = acc[c];
}

// ---------------- frontier marking ----------------
__global__ void markA(const int* __restrict__ wi_rows, const int* __restrict__ wi_cols,
                      int* __restrict__ flagR2, int e, int n) {
    int i = blockIdx.x * blockDim.x + threadIdx.x;
    if (i >= e) return;
    if (wi_rows[i] >= n - 2) flagR2[wi_cols[i]] = 1;
}
__global__ void markB(const int* __restrict__ w_rows, const int* __restrict__ w_cols,
                      const int* __restrict__ flagR2, int* __restrict__ flagN1, int e) {
    int i = blockIdx.x * blockDim.x + threadIdx.x;
    if (i >= e) return;
    if (flagR2[w_rows[i]]) flagN1[w_cols[i]] = 1;
}
__global__ void markC(const int* __restrict__ wi_rows, const int* __restrict__ wi_cols,
                      const int* __restrict__ flagN1, int* __restrict__ flagR1, int e) {
    int i = blockIdx.x * blockDim.x + threadIdx.x;
    if (i >= e) return;
    if (flagN1[wi_rows[i]]) flagR1[wi_cols[i]] = 1;
}
__global__ void union_flags(const int* __restrict__ a, const int* __restrict__ b,
                            int* __restrict__ u, int n) {
    int i = blockIdx.x * blockDim.x + threadIdx.x;
    if (i < n) u[i] = a[i] | b[i];
}

// ---------------- fused flag-gated histograms ----------------
__global__ void hist_both(const int* __restrict__ w_rows, const int* __restrict__ wi_rows,
                          const int* __restrict__ flagU, const int* __restrict__ flagN1,
                          int* __restrict__ w_cnt, int* __restrict__ wi_cnt, int e) {
    int i = blockIdx.x * blockDim.x + threadIdx.x;
    if (i >= e) return;
    int r = w_rows[i];
    if (flagU[r]) atomicAdd(&w_cnt[r], 1);
    int n = wi_rows[i];
    if (flagN1[n]) atomicAdd(&wi_cnt[n], 1);
}

// ---------------- segment assignment: off[i] = base for cnt[i] (order-free) ----
__global__ void assign_offsets(const int* __restrict__ cnt, int n,
                               int* __restrict__ off, int* __restrict__ gcur) {
    int i = blockIdx.x * 256 + threadIdx.x;
    int tid = threadIdx.x;
    int v = (i < n) ? cnt[i] : 0;
    __shared__ int s[256];
    s[tid] = v;
    __syncthreads();
#pragma unroll
    for (int d = 1; d < 256; d <<= 1) {
        int t = (tid >= d) ? s[tid - d] : 0;
        __syncthreads();
        s[tid] += t;
        __syncthreads();
    }
    int incl = s[tid];
    __shared__ int base;
    if (tid == 255) base = atomicAdd(gcur, incl);
    __syncthreads();
    if (i < n) off[i] = base + incl - v;
}

// ---------------- fused flag-gated placement (packs col+val in CSR order) ------
__global__ void place_both(const int* __restrict__ w_rows, const int* __restrict__ w_cols,
                           const float* __restrict__ w_val,
                           const int* __restrict__ wi_rows, const int* __restrict__ wi_cols,
                           const float* __restrict__ wi_val, const float* __restrict__ diag1,
                           const int* __restrict__ flagU, const int* __restrict__ flagN1,
                           const int* __restrict__ w_off, int* __restrict__ w_cur,
                           const int* __restrict__ wi_off, int* __restrict__ wi_cur,
                           int* __restrict__ w_cols_s, float* __restrict__ w_vals_s,
                           int* __restrict__ wi_cols_s, float* __restrict__ wi_coef_s,
                           int e) {
    int i = blockIdx.x * blockDim.x + threadIdx.x;
    if (i >= e) return;
    int r = w_rows[i];
    if (flagU[r]) {
        int pos = w_off[r] + atomicAdd(&w_cur[r], 1);
        w_cols_s[pos] = w_cols[i];
        w_vals_s[pos] = w_val[i];
    }
    int n = wi_rows[i];
    if (flagN1[n]) {
        int pos = wi_off[n] + atomicAdd(&wi_cur[n], 1);
        if (pos < WI_CAP) {
            int c = wi_cols[i];
            wi_cols_s[pos] = c;
            wi_coef_s[pos] = wi_val[i] * diag1[c];
        }
    }
}

// ------------- flag-gated CSR gather (packed): dst[b,row,:] = sum val*src[b,col,:]
template<int C>
__global__ void gather_rows(const float* __restrict__ src, float* __restrict__ dst,
                            const int* __restrict__ off, const int* __restrict__ len,
                            const int* __restrict__ cols_s, const float* __restrict__ vals_s,
                            const int* __restrict__ flag, int nRows, int srcN) {
    int tid = blockIdx.x * blockDim.x + threadIdx.x;
    int g = tid / C;
    int c = tid - g * C;
    int row = g >> 2;          // B == 4
    int b = g & 3;
    if (row >= nRows) return;
    if (!flag[row]) return;
    int s = off[row];
    int L = len[row];
    const float* sb = src + (size_t)b * srcN * C + c;
    float acc = 0.f;
    for (int i = s; i < s + L; ++i) {
        acc += vals_s[i] * sb[(size_t)cols_s[i] * C];
    }
    dst[((size_t)b * nRows + row) * C + c] = acc;
}

// ------------- x2 accumulation: edges into rows N-2/N-1 (few pass) ---------------
__global__ void x2_scan(const float* __restrict__ t2, float* __restrict__ x2buf,
                        const int* __restrict__ wi_rows, const int* __restrict__ wi_cols,
                        const float* __restrict__ wi_val, const float* __restrict__ diag,
                        int e, int n) {
    int ed = blockIdx.x * blockDim.x + threadIdx.x;
    if (ed >= e) return;
    int row = wi_rows[ed];
    if (row < n - 2) return;
    int which = row - (n - 2);
    int col = wi_cols[ed];
    float coef = wi_val[ed] * diag[col];
#pragma unroll
    for (int b = 0; b < B; ++b) {
        const float* sp = t2 + ((size_t)b * R + col) * 16;
        float* dp = x2buf + (b * 2 + which) * 16;
#pragma unroll
        for (int c = 0; c < 16; ++c) atomicAdd(dp + c, coef * sp[c]);
    }
}

// ---------------- heads ----------------
__global__ void heads_kernel(const float* __restrict__ x2buf,
                             const float* __restrict__ w1, const float* __restrict__ b1,
                             const float* __restrict__ w2, const float* __restrict__ b2,
                             float* __restrict__ out) {
    int i = threadIdx.x;
    if (i >= 2 * B) return;
    int b = i >> 1, which = i & 1;
    const float* xr = x2buf + (b * 2 + which) * 16;
    const float* w = which ? w2 : w1;
    float acc = which ? b2[0] : b1[0];
    for (int k = 0; k < 16; ++k) {
        float xv = xr[k];
        xv = xv > 0.f ? xv : NEG_SLOPE * xv;
        acc += xv * w[k];
    }
    out[b * 2 + which] = acc;
}

extern "C" void kernel_launch(void* const* d_in, const int* in_sizes, int n_in,
                              void* d_out, int out_size, void* d_ws, size_t ws_size,
                              hipStream_t stream) {
    const int*   w_rows  = (const int*)d_in[0];
    const int*   w_cols  = ((const int*)d_in[0]) + E;
    const float* w_val   = (const float*)d_in[1];
    const int*   wi_rows = (const int*)d_in[2];
    const int*   wi_cols = ((const int*)d_in[2]) + E;
    const float* wi_val  = (const float*)d_in[3];
    const float* x       = (const float*)d_in[4];
    const float* W1      = (const float*)d_in[5];
    const float* diag1   = (const float*)d_in[6];
    const float* W2      = (const float*)d_in[7];
    const float* diag2   = (const float*)d_in[8];
    const float* rw1     = (const float*)d_in[9];
    const float* rb1     = (const float*)d_in[10];
    const float* rw2     = (const float*)d_in[11];
    const float* rb2     = (const float*)d_in[12];
    float* out = (float*)d_out;

    // ---------------- workspace layout ----------------
    float* h1   = (float*)d_ws;                 // B*N*32; later aliased as x1
    float* treg = h1 + (size_t)B * N * 32;      // B*R*32: t1; later h2 [0..B*N*16), t2 [B*N*16..)
    int* ip = (int*)(treg + (size_t)B * R * 32);
    // zeroed block (contiguous):
    int* w_cnt  = ip; ip += R;
    int* w_off  = ip; ip += R;
    int* w_cur  = ip; ip += R;
    int* wi_cnt = ip; ip += N;
    int* wi_off = ip; ip += N;
    int* wi_cur = ip; ip += N;
    int* flagR2 = ip; ip += R;
    int* flagN1 = ip; ip += N;
    int* flagR1 = ip; ip += R;
    int* flagU  = ip; ip += R;
    int* gcur   = ip; ip += 2;
    float* x2buf = (float*)ip; ip += 2 * B * 16;
    size_t zero_words = (size_t)(ip - w_cnt);
    // un-zeroed packed arrays:
    int*   w_cols_s  = ip; ip += E;
    float* w_vals_s  = (float*)ip; ip += E;
    int*   wi_cols_s = ip; ip += WI_CAP;
    float* wi_coef_s = (float*)ip; ip += WI_CAP;

    float* x1 = h1;
    float* h2 = treg;
    float* t2 = treg + (size_t)B * N * 16;

    const int blk = 256;
    const int egrid = (E + blk - 1) / blk;
    const int rgrid = (R + blk - 1) / blk;
    const int ngrid = (N + blk - 1) / blk;

    hipMemsetAsync(w_cnt, 0, zero_words * sizeof(int), stream);

    // ---- frontier marking ----
    markA<<<egrid, blk, 0, stream>>>(wi_rows, wi_cols, flagR2, E, N);
    markB<<<egrid, blk, 0, stream>>>(w_rows, w_cols, flagR2, flagN1, E);
    markC<<<egrid, blk, 0, stream>>>(wi_rows, wi_cols, flagN1, flagR1, E);
    union_flags<<<rgrid, blk, 0, stream>>>(flagR1, flagR2, flagU, R);

    // ---- CSR builds (both, fused; flag-gated) ----
    hist_both<<<egrid, blk, 0, stream>>>(w_rows, wi_rows, flagU, flagN1, w_cnt, wi_cnt, E);
    assign_offsets<<<rgrid, 256, 0, stream>>>(w_cnt, R, w_off, gcur + 0);
    assign_offsets<<<ngrid, 256, 0, stream>>>(wi_cnt, N, wi_off, gcur + 1);
    place_both<<<egrid, blk, 0, stream>>>(w_rows, w_cols, w_val,
                                          wi_rows, wi_cols, wi_val, diag1,
                                          flagU, flagN1, w_off, w_cur, wi_off, wi_cur,
                                          w_cols_s, w_vals_s, wi_cols_s, wi_coef_s, E);

    // ---- layer 1 ----
    gemm_rows<32, 32, false, false><<<(B * N + blk - 1) / blk, blk, 0, stream>>>(
        x, W1, h1, B * N, nullptr, N);
    gather_rows<32><<<((size_t)R * B * 32 + blk - 1) / blk, blk, 0, stream>>>(
        h1, treg, w_off, w_cnt, w_cols_s, w_vals_s, flagR1, R, N);       // t1
    gather_rows<32><<<((size_t)N * B * 32 + blk - 1) / blk, blk, 0, stream>>>(
        treg, x1, wi_off, wi_cnt, wi_cols_s, wi_coef_s, flagN1, N, R);   // x1 (diag1 in coef)

    // ---- layer 2 ----
    gemm_rows<32, 16, true, true><<<(B * N + blk - 1) / blk, blk, 0, stream>>>(
        x1, W2, h2, B * N, flagN1, N);
    gather_rows<16><<<((size_t)R * B * 16 + blk - 1) / blk, blk, 0, stream>>>(
        h2, t2, w_off, w_cnt, w_cols_s, w_vals_s, flagR2, R, N);         // t2
    x2_scan<<<egrid, blk, 0, stream>>>(t2, x2buf, wi_rows, wi_cols, wi_val, diag2, E, N);
    heads_kernel<<<1, 64, 0, stream>>>(x2buf, rw1, rb1, rw2, rb2, out);
}

// Round 4
// 317.865 us; speedup vs baseline: 24.5087x; 1.3508x over previous
//
#include <hip/hip_runtime.h>

#define NEG_SLOPE 0.2f

static const int B = 4, N = 50000, R = 100000, E = 1600000;
static const int WI_CAP = 512 * 1024;   // packed wi-CSR capacity (actual ~33k, 16x margin)

// ---------------- dense per-row GEMM: out[r, :H] = f(x[r, :DIN]) @ W -----------
template<int DIN, int H, bool RELU_IN, bool USE_FLAG>
__global__ void gemm_rows(const float* __restrict__ x, const float* __restrict__ W,
                          float* __restrict__ out, int nRows,
                          const int* __restrict__ flag, int rowsPerBatch) {
    __shared__ float sW[DIN * H];
    for (int i = threadIdx.x; i < DIN * H; i += blockDim.x) sW[i] = W[i];
    __syncthreads();
    int row = blockIdx.x * blockDim.x + threadIdx.x;
    if (row >= nRows) return;
    if (USE_FLAG) {
        int n = row % rowsPerBatch;
        if (!flag[n]) return;
    }
    const float* xr = x + (size_t)row * DIN;
    float acc[H];
#pragma unroll
    for (int c = 0; c < H; ++c) acc[c] = 0.f;
#pragma unroll
    for (int k = 0; k < DIN; ++k) {
        float xv = xr[k];
        if (RELU_IN) xv = xv > 0.f ? xv : NEG_SLOPE * xv;
#pragma unroll
        for (int c = 0; c < H; ++c) acc[c] += xv * sW[k * H + c];
    }
    float* o = out + (size_t)row * H;
#pragma unroll
    for (int c = 0; c < H; ++c) o[c] = acc[c];
}

// ---------------- frontier marking (int4-vectorized E-scans) ----------------
__global__ void markA(const int4* __restrict__ wi_rows4, const int* __restrict__ wi_cols,
                      int* __restrict__ flagR2, int e4, int n) {
    int i = blockIdx.x * blockDim.x + threadIdx.x;
    if (i >= e4) return;
    int4 r = wi_rows4[i];
    int base = i * 4;
    if (r.x >= n - 2) flagR2[wi_cols[base + 0]] = 1;
    if (r.y >= n - 2) flagR2[wi_cols[base + 1]] = 1;
    if (r.z >= n - 2) flagR2[wi_cols[base + 2]] = 1;
    if (r.w >= n - 2) flagR2[wi_cols[base + 3]] = 1;
}
__global__ void markB(const int4* __restrict__ w_rows4, const int* __restrict__ w_cols,
                      const int* __restrict__ flagR2, int* __restrict__ flagN1, int e4) {
    int i = blockIdx.x * blockDim.x + threadIdx.x;
    if (i >= e4) return;
    int4 r = w_rows4[i];
    int base = i * 4;
    if (flagR2[r.x]) flagN1[w_cols[base + 0]] = 1;
    if (flagR2[r.y]) flagN1[w_cols[base + 1]] = 1;
    if (flagR2[r.z]) flagN1[w_cols[base + 2]] = 1;
    if (flagR2[r.w]) flagN1[w_cols[base + 3]] = 1;
}
__global__ void markC(const int4* __restrict__ wi_rows4, const int* __restrict__ wi_cols,
                      const int* __restrict__ flagN1, int* __restrict__ flagR1, int e4) {
    int i = blockIdx.x * blockDim.x + threadIdx.x;
    if (i >= e4) return;
    int4 r = wi_rows4[i];
    int base = i * 4;
    if (flagN1[r.x]) flagR1[wi_cols[base + 0]] = 1;
    if (flagN1[r.y]) flagR1[wi_cols[base + 1]] = 1;
    if (flagN1[r.z]) flagR1[wi_cols[base + 2]] = 1;
    if (flagN1[r.w]) flagR1[wi_cols[base + 3]] = 1;
}

// ---------------- fused flag-gated histograms (flagU computed inline) ----------
__global__ void hist_both(const int4* __restrict__ w_rows4, const int4* __restrict__ wi_rows4,
                          const int* __restrict__ flagR1, const int* __restrict__ flagR2,
                          const int* __restrict__ flagN1,
                          int* __restrict__ w_cnt, int* __restrict__ wi_cnt, int e4) {
    int i = blockIdx.x * blockDim.x + threadIdx.x;
    if (i >= e4) return;
    int4 r = w_rows4[i];
    if (flagR1[r.x] | flagR2[r.x]) atomicAdd(&w_cnt[r.x], 1);
    if (flagR1[r.y] | flagR2[r.y]) atomicAdd(&w_cnt[r.y], 1);
    if (flagR1[r.z] | flagR2[r.z]) atomicAdd(&w_cnt[r.z], 1);
    if (flagR1[r.w] | flagR2[r.w]) atomicAdd(&w_cnt[r.w], 1);
    int4 nn = wi_rows4[i];
    if (flagN1[nn.x]) atomicAdd(&wi_cnt[nn.x], 1);
    if (flagN1[nn.y]) atomicAdd(&wi_cnt[nn.y], 1);
    if (flagN1[nn.z]) atomicAdd(&wi_cnt[nn.z], 1);
    if (flagN1[nn.w]) atomicAdd(&wi_cnt[nn.w], 1);
}

// ------- segment base assignment for both CSRs in one dispatch (order-free) -----
__global__ void assign_offsets2(const int* __restrict__ cntA, int nA, int* __restrict__ offA,
                                const int* __restrict__ cntB, int nB, int* __restrict__ offB,
                                int* __restrict__ gcur) {
    int nBlocksA = (nA + 255) / 256;
    bool isA = (int)blockIdx.x < nBlocksA;
    const int* cnt = isA ? cntA : cntB;
    int* off = isA ? offA : offB;
    int n = isA ? nA : nB;
    int* gc = gcur + (isA ? 0 : 1);
    int blk = isA ? blockIdx.x : (blockIdx.x - nBlocksA);
    int i = blk * 256 + threadIdx.x;
    int tid = threadIdx.x;
    int v = (i < n) ? cnt[i] : 0;
    __shared__ int s[256];
    s[tid] = v;
    __syncthreads();
#pragma unroll
    for (int d = 1; d < 256; d <<= 1) {
        int t = (tid >= d) ? s[tid - d] : 0;
        __syncthreads();
        s[tid] += t;
        __syncthreads();
    }
    int incl = s[tid];
    __shared__ int base;
    if (tid == 255) base = atomicAdd(gc, incl);
    __syncthreads();
    if (i < n) off[i] = base + incl - v;
}

// ------- fused flag-gated placement; packs (col, coef) int2 pairs in CSR order ---
__global__ void place_both(const int* __restrict__ w_rows, const int* __restrict__ w_cols,
                           const float* __restrict__ w_val,
                           const int* __restrict__ wi_rows, const int* __restrict__ wi_cols,
                           const float* __restrict__ wi_val, const float* __restrict__ diag1,
                           const int* __restrict__ flagR1, const int* __restrict__ flagR2,
                           const int* __restrict__ flagN1,
                           const int* __restrict__ w_off, int* __restrict__ w_cur,
                           const int* __restrict__ wi_off, int* __restrict__ wi_cur,
                           int2* __restrict__ w_pairs, int2* __restrict__ wi_pairs, int e) {
    int i = blockIdx.x * blockDim.x + threadIdx.x;
    if (i >= e) return;
    int r = w_rows[i];
    if (flagR1[r] | flagR2[r]) {
        int pos = w_off[r] + atomicAdd(&w_cur[r], 1);
        w_pairs[pos] = make_int2(w_cols[i], __float_as_int(w_val[i]));
    }
    int n = wi_rows[i];
    if (flagN1[n]) {
        int pos = wi_off[n] + atomicAdd(&wi_cur[n], 1);
        if (pos < WI_CAP) {
            int c = wi_cols[i];
            wi_pairs[pos] = make_int2(c, __float_as_int(wi_val[i] * diag1[c]));
        }
    }
}

// ------- flag-gated CSR gather, float4 per thread, edge loop unrolled x4 --------
// dst[b,row,:] = sum_i coef_i * src[b,col_i,:]
template<int C>
__global__ void gather_rows(const float* __restrict__ src, float* __restrict__ dst,
                            const int* __restrict__ off, const int* __restrict__ len,
                            const int2* __restrict__ pairs, const int* __restrict__ flag,
                            int nRows, int srcN) {
    constexpr int C4 = C / 4;             // float4 groups per row
    constexpr int TPR = C4 * B;           // threads per row
    int tid = blockIdx.x * blockDim.x + threadIdx.x;
    int row = tid / TPR;
    int rem = tid - row * TPR;
    int c4 = rem & (C4 - 1);
    int b  = rem / C4;
    if (row >= nRows) return;
    if (!flag[row]) return;
    int s = off[row];
    int L = len[row];
    const float4* sb = (const float4*)src + (size_t)b * srcN * C4 + c4;
    float4 acc = make_float4(0.f, 0.f, 0.f, 0.f);
    int i = s;
    int e4 = s + (L & ~3);
    for (; i < e4; i += 4) {
        int2 p0 = pairs[i + 0];
        int2 p1 = pairs[i + 1];
        int2 p2 = pairs[i + 2];
        int2 p3 = pairs[i + 3];
        float4 s0 = sb[(size_t)p0.x * C4];
        float4 s1 = sb[(size_t)p1.x * C4];
        float4 s2 = sb[(size_t)p2.x * C4];
        float4 s3 = sb[(size_t)p3.x * C4];
        float v0 = __int_as_float(p0.y), v1 = __int_as_float(p1.y);
        float v2 = __int_as_float(p2.y), v3 = __int_as_float(p3.y);
        acc.x += v0 * s0.x + v1 * s1.x + v2 * s2.x + v3 * s3.x;
        acc.y += v0 * s0.y + v1 * s1.y + v2 * s2.y + v3 * s3.y;
        acc.z += v0 * s0.z + v1 * s1.z + v2 * s2.z + v3 * s3.z;
        acc.w += v0 * s0.w + v1 * s1.w + v2 * s2.w + v3 * s3.w;
    }
    for (; i < s + L; ++i) {
        int2 p = pairs[i];
        float4 sv = sb[(size_t)p.x * C4];
        float v = __int_as_float(p.y);
        acc.x += v * sv.x; acc.y += v * sv.y; acc.z += v * sv.z; acc.w += v * sv.w;
    }
    ((float4*)dst)[((size_t)b * nRows + row) * C4 + c4] = acc;
}

// ------------- x2 accumulation: edges into rows N-2/N-1 (few pass) ---------------
__global__ void x2_scan(const float* __restrict__ t2, float* __restrict__ x2buf,
                        const int4* __restrict__ wi_rows4, const int* __restrict__ wi_cols,
                        const float* __restrict__ wi_val, const float* __restrict__ diag,
                        int e4, int n) {
    int i = blockIdx.x * blockDim.x + threadIdx.x;
    if (i >= e4) return;
    int4 r = wi_rows4[i];
    int rr[4] = {r.x, r.y, r.z, r.w};
#pragma unroll
    for (int k = 0; k < 4; ++k) {
        int row = rr[k];
        if (row < n - 2) continue;
        int ed = i * 4 + k;
        int which = row - (n - 2);
        int col = wi_cols[ed];
        float coef = wi_val[ed] * diag[col];
        for (int b = 0; b < B; ++b) {
            const float* sp = t2 + ((size_t)b * R + col) * 16;
            float* dp = x2buf + (b * 2 + which) * 16;
            for (int c = 0; c < 16; ++c) atomicAdd(dp + c, coef * sp[c]);
        }
    }
}

// ---------------- heads ----------------
__global__ void heads_kernel(const float* __restrict__ x2buf,
                             const float* __restrict__ w1, const float* __restrict__ b1,
                             const float* __restrict__ w2, const float* __restrict__ b2,
                             float* __restrict__ out) {
    int i = threadIdx.x;
    if (i >= 2 * B) return;
    int b = i >> 1, which = i & 1;
    const float* xr = x2buf + (b * 2 + which) * 16;
    const float* w = which ? w2 : w1;
    float acc = which ? b2[0] : b1[0];
    for (int k = 0; k < 16; ++k) {
        float xv = xr[k];
        xv = xv > 0.f ? xv : NEG_SLOPE * xv;
        acc += xv * w[k];
    }
    out[b * 2 + which] = acc;
}

extern "C" void kernel_launch(void* const* d_in, const int* in_sizes, int n_in,
                              void* d_out, int out_size, void* d_ws, size_t ws_size,
                              hipStream_t stream) {
    const int*   w_rows  = (const int*)d_in[0];
    const int*   w_cols  = ((const int*)d_in[0]) + E;
    const float* w_val   = (const float*)d_in[1];
    const int*   wi_rows = (const int*)d_in[2];
    const int*   wi_cols = ((const int*)d_in[2]) + E;
    const float* wi_val  = (const float*)d_in[3];
    const float* x       = (const float*)d_in[4];
    const float* W1      = (const float*)d_in[5];
    const float* diag1   = (const float*)d_in[6];
    const float* W2      = (const float*)d_in[7];
    const float* diag2   = (const float*)d_in[8];
    const float* rw1     = (const float*)d_in[9];
    const float* rb1     = (const float*)d_in[10];
    const float* rw2     = (const float*)d_in[11];
    const float* rb2     = (const float*)d_in[12];
    float* out = (float*)d_out;

    // ---------------- workspace layout ----------------
    float* h1   = (float*)d_ws;                 // B*N*32; later aliased as x1
    float* treg = h1 + (size_t)B * N * 32;      // B*R*32: t1; later h2 [0..B*N*16), t2 [B*N*16..)
    int* ip = (int*)(treg + (size_t)B * R * 32);
    // zeroed block (contiguous):
    int* w_cnt  = ip; ip += R;
    int* w_off  = ip; ip += R;
    int* w_cur  = ip; ip += R;
    int* wi_cnt = ip; ip += N;
    int* wi_off = ip; ip += N;
    int* wi_cur = ip; ip += N;
    int* flagR2 = ip; ip += R;
    int* flagN1 = ip; ip += N;
    int* flagR1 = ip; ip += R;
    int* gcur   = ip; ip += 2;
    float* x2buf = (float*)ip; ip += 2 * B * 16;
    size_t zero_words = (size_t)(ip - w_cnt);
    // un-zeroed packed pair arrays (8B aligned: offset from d_ws is even #ints):
    int2* w_pairs  = (int2*)ip; ip += 2 * E;
    int2* wi_pairs = (int2*)ip; ip += 2 * WI_CAP;

    float* x1 = h1;
    float* h2 = treg;
    float* t2 = treg + (size_t)B * N * 16;

    const int blk = 256;
    const int E4 = E / 4;                       // E = 1.6M, divisible by 4
    const int e4grid = (E4 + blk - 1) / blk;
    const int egrid = (E + blk - 1) / blk;

    hipMemsetAsync(w_cnt, 0, zero_words * sizeof(int), stream);

    // ---- frontier marking ----
    markA<<<e4grid, blk, 0, stream>>>((const int4*)wi_rows, wi_cols, flagR2, E4, N);
    markB<<<e4grid, blk, 0, stream>>>((const int4*)w_rows, w_cols, flagR2, flagN1, E4);
    markC<<<e4grid, blk, 0, stream>>>((const int4*)wi_rows, wi_cols, flagN1, flagR1, E4);

    // ---- CSR builds (both, fused; flag-gated; flagU inline) ----
    hist_both<<<e4grid, blk, 0, stream>>>((const int4*)w_rows, (const int4*)wi_rows,
                                          flagR1, flagR2, flagN1, w_cnt, wi_cnt, E4);
    {
        int nBlocks = (R + 255) / 256 + (N + 255) / 256;
        assign_offsets2<<<nBlocks, 256, 0, stream>>>(w_cnt, R, w_off, wi_cnt, N, wi_off, gcur);
    }
    place_both<<<egrid, blk, 0, stream>>>(w_rows, w_cols, w_val,
                                          wi_rows, wi_cols, wi_val, diag1,
                                          flagR1, flagR2, flagN1,
                                          w_off, w_cur, wi_off, wi_cur,
                                          w_pairs, wi_pairs, E);

    // ---- layer 1 ----
    gemm_rows<32, 32, false, false><<<(B * N + blk - 1) / blk, blk, 0, stream>>>(
        x, W1, h1, B * N, nullptr, N);
    gather_rows<32><<<((size_t)R * 32 + blk - 1) / blk, blk, 0, stream>>>(
        h1, treg, w_off, w_cnt, w_pairs, flagR1, R, N);          // t1
    gather_rows<32><<<((size_t)N * 32 + blk - 1) / blk, blk, 0, stream>>>(
        treg, x1, wi_off, wi_cnt, wi_pairs, flagN1, N, R);       // x1 (diag1 folded in coef)

    // ---- layer 2 ----
    gemm_rows<32, 16, true, true><<<(B * N + blk - 1) / blk, blk, 0, stream>>>(
        x1, W2, h2, B * N, flagN1, N);
    gather_rows<16><<<((size_t)R * 16 + blk - 1) / blk, blk, 0, stream>>>(
        h2, t2, w_off, w_cnt, w_pairs, flagR2, R, N);            // t2
    x2_scan<<<e4grid, blk, 0, stream>>>(t2, x2buf, (const int4*)wi_rows, wi_cols,
                                        wi_val, diag2, E4, N);
    heads_kernel<<<1, 64, 0, stream>>>(x2buf, rw1, rb1, rw2, rb2, out);
}